// Round 3
// baseline (590.145 us; speedup 1.0000x reference)
//
#include <hip/hip_runtime.h>

#define B_ 2
#define S_ 2048
#define D_ 64
#define H_ 8
#define WAVES 4
#define TPW 16   // t-tiles (of 32) per wave

typedef __bf16 bf16x8 __attribute__((ext_vector_type(8)));
typedef float  f32x16 __attribute__((ext_vector_type(16)));
typedef float  f32x4  __attribute__((ext_vector_type(4)));
typedef unsigned int u32x4 __attribute__((ext_vector_type(4)));

// 0.125*log2(e) and log2(e)
#define C_QK 0.18033688011112042f
#define C_B  1.4426950408889634f

__device__ __forceinline__ unsigned int pkbf(float a, float b) {
    __bf16 x = (__bf16)a, y = (__bf16)b;
    unsigned short ux = __builtin_bit_cast(unsigned short, x);
    unsigned short uy = __builtin_bit_cast(unsigned short, y);
    return (unsigned int)ux | ((unsigned int)uy << 16);
}

__global__ __launch_bounds__(256, 4) void attn_kernel(
    const float* __restrict__ x1, const float* __restrict__ x2,
    const float* __restrict__ x3, const float* __restrict__ x4,
    float* __restrict__ out)
{
    // [w][d][q] f32 partial O; lanes vary q on both write and read -> conflict-free
    __shared__ float sO[WAVES][D_][32];   // 32 KB
    __shared__ float sm[WAVES][32];
    __shared__ float sl[WAVES][32];

    const int tid  = threadIdx.x;
    const int w    = tid >> 6;           // wave id 0..3
    const int lane = tid & 63;
    const int lo = lane & 31;
    const int hi = lane >> 5;

    const int bid = blockIdx.x;          // 0..1023
    const int b   = bid >> 9;
    const int rem = bid & 511;
    const int h   = rem >> 6;
    const int qt  = rem & 63;
    const int qbase = qt * 32;

    // ---- persistent Q fragments (B-operand of QK mfma) ----
    const float* qrow = x1 + ((size_t)b * S_ + qbase + lo) * D_ + 8 * hi;
    bf16x8 Qf[4];
#pragma unroll
    for (int kk = 0; kk < 4; ++kk) {
        f32x4 qa = *(const f32x4*)(qrow + 16 * kk);
        f32x4 qb = *(const f32x4*)(qrow + 16 * kk + 4);
#pragma unroll
        for (int i = 0; i < 4; ++i) {
            Qf[kk][i]     = (__bf16)qa[i];
            Qf[kk][4 + i] = (__bf16)qb[i];
        }
    }

    // ---- per-wave flash state ----
    f32x16 O0, O1;
#pragma unroll
    for (int i = 0; i < 16; ++i) { O0[i] = 0.f; O1[i] = 0.f; }
    float m_run = -3.0e38f;
    float l_run = 0.f;

    const float* brow = x3 + (((size_t)(b * H_ + h) * S_) + qbase + lo) * S_ + 4 * hi;

    auto load_bias = [&](int t, f32x4* dst) {
        const float* p = brow + t * 32;
#pragma unroll
        for (int g = 0; g < 4; ++g) dst[g] = *(const f32x4*)(p + 8 * g);
    };

    auto mk_pfrag = [&](const float* p) -> bf16x8 {
        int a0 = (int)pkbf(p[0], p[1]), a1 = (int)pkbf(p[2], p[3]);
        int b0 = (int)pkbf(p[4], p[5]), b1 = (int)pkbf(p[6], p[7]);
        int s0 = hi ? a0 : b0, s1 = hi ? a1 : b1;
        int r0 = __shfl_xor(s0, 32);
        int r1 = __shfl_xor(s1, 32);
        u32x4 f;
        f[0] = (unsigned int)(hi ? r0 : a0);
        f[1] = (unsigned int)(hi ? r1 : a1);
        f[2] = (unsigned int)(hi ? b0 : r0);
        f[3] = (unsigned int)(hi ? b1 : r1);
        return __builtin_bit_cast(bf16x8, f);
    };

    auto compute = [&](int t, const f32x4* bias) {
        const int tb = t * 32;

        // K tile (L2-resident): A-frag slot (hi,i): K[tb+lo][16kk+8hi+i]
        const float* krow = x2 + ((size_t)b * S_ + tb + lo) * D_ + 8 * hi;
        f32x4 kraw[8];
#pragma unroll
        for (int kk = 0; kk < 4; ++kk) {
            kraw[2 * kk]     = *(const f32x4*)(krow + 16 * kk);
            kraw[2 * kk + 1] = *(const f32x4*)(krow + 16 * kk + 4);
        }
        // V raw: V[tb+16*g2+8*hi+i][32*dh+lo]
        float vraw[4][8];
#pragma unroll
        for (int g2 = 0; g2 < 2; ++g2) {
#pragma unroll
            for (int dh = 0; dh < 2; ++dh) {
                const float* vb = x4 + ((size_t)b * S_ + tb + 16 * g2 + 8 * hi) * D_ + 32 * dh + lo;
#pragma unroll
                for (int i = 0; i < 8; ++i) vraw[2 * g2 + dh][i] = vb[i * D_];
            }
        }

        // QK^T (S^T tile: D[r=t][c=q])
        f32x16 acc;
#pragma unroll
        for (int i = 0; i < 16; ++i) acc[i] = 0.f;
#pragma unroll
        for (int kk = 0; kk < 4; ++kk) {
            bf16x8 kf;
#pragma unroll
            for (int i = 0; i < 4; ++i) {
                kf[i]     = (__bf16)kraw[2 * kk][i];
                kf[4 + i] = (__bf16)kraw[2 * kk + 1][i];
            }
            acc = __builtin_amdgcn_mfma_f32_32x32x16_bf16(kf, Qf[kk], acc, 0, 0, 0);
        }

        float s[16];
#pragma unroll
        for (int r = 0; r < 16; ++r)
            s[r] = acc[r] * C_QK + bias[r >> 2][r & 3] * C_B;

        float pmax = s[0];
#pragma unroll
        for (int r = 1; r < 16; ++r) pmax = fmaxf(pmax, s[r]);
        pmax = fmaxf(pmax, __shfl_xor(pmax, 32));

        if (__any(pmax > m_run)) {
            float mnew = fmaxf(m_run, pmax);
            float sc = __builtin_amdgcn_exp2f(m_run - mnew);
#pragma unroll
            for (int r = 0; r < 16; ++r) { O0[r] *= sc; O1[r] *= sc; }
            l_run *= sc;
            m_run = mnew;
        }

        float p[16];
        float ls = 0.f;
#pragma unroll
        for (int r = 0; r < 16; ++r) {
            p[r] = __builtin_amdgcn_exp2f(s[r] - m_run);
            ls += p[r];
        }
        l_run += ls;

#pragma unroll
        for (int g2 = 0; g2 < 2; ++g2) {
            bf16x8 pf = mk_pfrag(p + 8 * g2);
#pragma unroll
            for (int dh = 0; dh < 2; ++dh) {
                bf16x8 vf;
#pragma unroll
                for (int i = 0; i < 8; ++i) vf[i] = (__bf16)vraw[2 * g2 + dh][i];
                if (dh == 0) O0 = __builtin_amdgcn_mfma_f32_32x32x16_bf16(vf, pf, O0, 0, 0, 0);
                else         O1 = __builtin_amdgcn_mfma_f32_32x32x16_bf16(vf, pf, O1, 0, 0, 0);
            }
        }
    };

    // ---- main loop: wave w handles t-tiles [w*TPW, (w+1)*TPW) ----
    const int t0 = w * TPW;
    f32x4 bA[4], bB[4];
    load_bias(t0, bA);
    for (int t = t0; t < t0 + TPW; t += 2) {
        load_bias(t + 1, bB);
        compute(t, bA);
        if (t + 2 < t0 + TPW) load_bias(t + 2, bA);
        compute(t + 1, bB);
    }

    // ---- cross-wave flash combine ----
    float l_tot = l_run + __shfl_xor(l_run, 32);   // per q=lo
    if (hi == 0) { sm[w][lo] = m_run; sl[w][lo] = l_tot; }
    __syncthreads();

    float M = fmaxf(fmaxf(sm[0][lo], sm[1][lo]), fmaxf(sm[2][lo], sm[3][lo]));
    float scale = __builtin_amdgcn_exp2f(m_run - M);
    float Lsum = 0.f;
#pragma unroll
    for (int w2 = 0; w2 < WAVES; ++w2)
        Lsum += sl[w2][lo] * __builtin_amdgcn_exp2f(sm[w2][lo] - M);

    // write scaled partial O: [w][d][q]
#pragma unroll
    for (int g = 0; g < 4; ++g) {
#pragma unroll
        for (int j = 0; j < 4; ++j) {
            int d = 8 * g + 4 * hi + j;
            sO[w][d][lo]      = O0[4 * g + j] * scale;
            sO[w][d + 32][lo] = O1[4 * g + j] * scale;
        }
    }
    __syncthreads();

    // combine: slice s = 2w+hi sums d in [8s, 8s+8), q = lo
    const float inv = 1.0f / Lsum;
    const int d0 = (2 * w + hi) * 8;
    f32x4 r0, r1;
#pragma unroll
    for (int i = 0; i < 4; ++i) {
        float a = sO[0][d0 + i][lo] + sO[1][d0 + i][lo]
                + sO[2][d0 + i][lo] + sO[3][d0 + i][lo];
        float c = sO[0][d0 + 4 + i][lo] + sO[1][d0 + 4 + i][lo]
                + sO[2][d0 + 4 + i][lo] + sO[3][d0 + 4 + i][lo];
        r0[i] = a * inv;
        r1[i] = c * inv;
    }
    float* orow = out + (((size_t)(b * H_ + h) * S_) + qbase + lo) * D_ + d0;
    *(f32x4*)orow       = r0;
    *(f32x4*)(orow + 4) = r1;
}

extern "C" void kernel_launch(void* const* d_in, const int* in_sizes, int n_in,
                              void* d_out, int out_size, void* d_ws, size_t ws_size,
                              hipStream_t stream) {
    const float* x1 = (const float*)d_in[0];
    const float* x2 = (const float*)d_in[1];
    const float* x3 = (const float*)d_in[2];
    const float* x4 = (const float*)d_in[3];
    float* o = (float*)d_out;
    hipLaunchKernelGGL(attn_kernel, dim3(B_ * H_ * (S_ / 32)), dim3(256), 0, stream,
                       x1, x2, x3, x4, o);
}

// Round 4
// 418.100 us; speedup vs baseline: 1.4115x; 1.4115x over previous
//
#include <hip/hip_runtime.h>

#define B_ 2
#define S_ 2048
#define D_ 64
#define H_ 8
#define WAVES 4
#define TPW 16   // t-tiles (of 32) per wave

typedef __bf16 bf16x8 __attribute__((ext_vector_type(8)));
typedef float  f32x16 __attribute__((ext_vector_type(16)));
typedef float  f32x4  __attribute__((ext_vector_type(4)));
typedef unsigned int u32x4 __attribute__((ext_vector_type(4)));

// 0.125*log2(e) and log2(e)
#define C_QK 0.18033688011112042f
#define C_B  1.4426950408889634f

__device__ __forceinline__ unsigned int pkbf(float a, float b) {
    __bf16 x = (__bf16)a, y = (__bf16)b;
    unsigned short ux = __builtin_bit_cast(unsigned short, x);
    unsigned short uy = __builtin_bit_cast(unsigned short, y);
    return (unsigned int)ux | ((unsigned int)uy << 16);
}

// NOTE: no min-waves arg — forcing (256,4) capped VGPR at 64 and produced
// 471 MB of scratch-spill traffic (round 3). Natural alloc ~100-110 VGPR
// already fits 4 waves/SIMD.
__global__ __launch_bounds__(256) void attn_kernel(
    const float* __restrict__ x1, const float* __restrict__ x2,
    const float* __restrict__ x3, const float* __restrict__ x4,
    float* __restrict__ out)
{
    // [w][d][q] f32 partial O; lanes vary q on both write and read -> conflict-free
    __shared__ float sO[WAVES][D_][32];   // 32 KB
    __shared__ float sm[WAVES][32];
    __shared__ float sl[WAVES][32];

    const int tid  = threadIdx.x;
    const int w    = tid >> 6;           // wave id 0..3
    const int lane = tid & 63;
    const int lo = lane & 31;
    const int hi = lane >> 5;

    const int bid = blockIdx.x;          // 0..1023
    const int b   = bid >> 9;
    const int rem = bid & 511;
    const int h   = rem >> 6;
    const int qt  = rem & 63;
    const int qbase = qt * 32;

    // ---- persistent Q fragments (B-operand of QK mfma) ----
    const float* qrow = x1 + ((size_t)b * S_ + qbase + lo) * D_ + 8 * hi;
    bf16x8 Qf[4];
#pragma unroll
    for (int kk = 0; kk < 4; ++kk) {
        f32x4 qa = *(const f32x4*)(qrow + 16 * kk);
        f32x4 qb = *(const f32x4*)(qrow + 16 * kk + 4);
#pragma unroll
        for (int i = 0; i < 4; ++i) {
            Qf[kk][i]     = (__bf16)qa[i];
            Qf[kk][4 + i] = (__bf16)qb[i];
        }
    }

    // ---- per-wave flash state ----
    f32x16 O0, O1;
#pragma unroll
    for (int i = 0; i < 16; ++i) { O0[i] = 0.f; O1[i] = 0.f; }
    float m_run = -3.0e38f;
    float l_run = 0.f;

    const float* brow = x3 + (((size_t)(b * H_ + h) * S_) + qbase + lo) * S_ + 4 * hi;

    auto load_bias = [&](int t, f32x4* dst) {
        const float* p = brow + t * 32;
#pragma unroll
        for (int g = 0; g < 4; ++g) dst[g] = *(const f32x4*)(p + 8 * g);
    };

    auto mk_pfrag = [&](const float* p) -> bf16x8 {
        int a0 = (int)pkbf(p[0], p[1]), a1 = (int)pkbf(p[2], p[3]);
        int b0 = (int)pkbf(p[4], p[5]), b1 = (int)pkbf(p[6], p[7]);
        int s0 = hi ? a0 : b0, s1 = hi ? a1 : b1;
        int r0 = __shfl_xor(s0, 32);
        int r1 = __shfl_xor(s1, 32);
        u32x4 f;
        f[0] = (unsigned int)(hi ? r0 : a0);
        f[1] = (unsigned int)(hi ? r1 : a1);
        f[2] = (unsigned int)(hi ? b0 : r0);
        f[3] = (unsigned int)(hi ? b1 : r1);
        return __builtin_bit_cast(bf16x8, f);
    };

    auto compute = [&](int t, const f32x4* bias) {
        const int tb = t * 32;

        // K tile (L2-resident): A-frag slot (hi,i): K[tb+lo][16kk+8hi+i]
        const float* krow = x2 + ((size_t)b * S_ + tb + lo) * D_ + 8 * hi;
        f32x4 kraw[8];
#pragma unroll
        for (int kk = 0; kk < 4; ++kk) {
            kraw[2 * kk]     = *(const f32x4*)(krow + 16 * kk);
            kraw[2 * kk + 1] = *(const f32x4*)(krow + 16 * kk + 4);
        }
        // V raw: V[tb+16*g2+8*hi+i][32*dh+lo]
        float vraw[4][8];
#pragma unroll
        for (int g2 = 0; g2 < 2; ++g2) {
#pragma unroll
            for (int dh = 0; dh < 2; ++dh) {
                const float* vb = x4 + ((size_t)b * S_ + tb + 16 * g2 + 8 * hi) * D_ + 32 * dh + lo;
#pragma unroll
                for (int i = 0; i < 8; ++i) vraw[2 * g2 + dh][i] = vb[i * D_];
            }
        }

        // QK^T (S^T tile: D[r=t][c=q])
        f32x16 acc;
#pragma unroll
        for (int i = 0; i < 16; ++i) acc[i] = 0.f;
#pragma unroll
        for (int kk = 0; kk < 4; ++kk) {
            bf16x8 kf;
#pragma unroll
            for (int i = 0; i < 4; ++i) {
                kf[i]     = (__bf16)kraw[2 * kk][i];
                kf[4 + i] = (__bf16)kraw[2 * kk + 1][i];
            }
            acc = __builtin_amdgcn_mfma_f32_32x32x16_bf16(kf, Qf[kk], acc, 0, 0, 0);
        }

        float s[16];
#pragma unroll
        for (int r = 0; r < 16; ++r)
            s[r] = acc[r] * C_QK + bias[r >> 2][r & 3] * C_B;

        float pmax = s[0];
#pragma unroll
        for (int r = 1; r < 16; ++r) pmax = fmaxf(pmax, s[r]);
        pmax = fmaxf(pmax, __shfl_xor(pmax, 32));

        if (__any(pmax > m_run)) {
            float mnew = fmaxf(m_run, pmax);
            float sc = __builtin_amdgcn_exp2f(m_run - mnew);
#pragma unroll
            for (int r = 0; r < 16; ++r) { O0[r] *= sc; O1[r] *= sc; }
            l_run *= sc;
            m_run = mnew;
        }

        float p[16];
        float ls = 0.f;
#pragma unroll
        for (int r = 0; r < 16; ++r) {
            p[r] = __builtin_amdgcn_exp2f(s[r] - m_run);
            ls += p[r];
        }
        l_run += ls;

#pragma unroll
        for (int g2 = 0; g2 < 2; ++g2) {
            bf16x8 pf = mk_pfrag(p + 8 * g2);
#pragma unroll
            for (int dh = 0; dh < 2; ++dh) {
                bf16x8 vf;
#pragma unroll
                for (int i = 0; i < 8; ++i) vf[i] = (__bf16)vraw[2 * g2 + dh][i];
                if (dh == 0) O0 = __builtin_amdgcn_mfma_f32_32x32x16_bf16(vf, pf, O0, 0, 0, 0);
                else         O1 = __builtin_amdgcn_mfma_f32_32x32x16_bf16(vf, pf, O1, 0, 0, 0);
            }
        }
    };

    // ---- main loop: wave w handles t-tiles [w*TPW, (w+1)*TPW) ----
    const int t0 = w * TPW;
    f32x4 bA[4], bB[4];
    load_bias(t0, bA);
    for (int t = t0; t < t0 + TPW; t += 2) {
        load_bias(t + 1, bB);
        compute(t, bA);
        if (t + 2 < t0 + TPW) load_bias(t + 2, bA);
        compute(t + 1, bB);
    }

    // ---- cross-wave flash combine ----
    float l_tot = l_run + __shfl_xor(l_run, 32);   // per q=lo
    if (hi == 0) { sm[w][lo] = m_run; sl[w][lo] = l_tot; }
    __syncthreads();

    float M = fmaxf(fmaxf(sm[0][lo], sm[1][lo]), fmaxf(sm[2][lo], sm[3][lo]));
    float scale = __builtin_amdgcn_exp2f(m_run - M);
    float Lsum = 0.f;
#pragma unroll
    for (int w2 = 0; w2 < WAVES; ++w2)
        Lsum += sl[w2][lo] * __builtin_amdgcn_exp2f(sm[w2][lo] - M);

    // write scaled partial O: [w][d][q]
#pragma unroll
    for (int g = 0; g < 4; ++g) {
#pragma unroll
        for (int j = 0; j < 4; ++j) {
            int d = 8 * g + 4 * hi + j;
            sO[w][d][lo]      = O0[4 * g + j] * scale;
            sO[w][d + 32][lo] = O1[4 * g + j] * scale;
        }
    }
    __syncthreads();

    // combine: slice s = 2w+hi sums d in [8s, 8s+8), q = lo
    const float inv = 1.0f / Lsum;
    const int d0 = (2 * w + hi) * 8;
    f32x4 r0, r1;
#pragma unroll
    for (int i = 0; i < 4; ++i) {
        float a = sO[0][d0 + i][lo] + sO[1][d0 + i][lo]
                + sO[2][d0 + i][lo] + sO[3][d0 + i][lo];
        float c = sO[0][d0 + 4 + i][lo] + sO[1][d0 + 4 + i][lo]
                + sO[2][d0 + 4 + i][lo] + sO[3][d0 + 4 + i][lo];
        r0[i] = a * inv;
        r1[i] = c * inv;
    }
    float* orow = out + (((size_t)(b * H_ + h) * S_) + qbase + lo) * D_ + d0;
    *(f32x4*)orow       = r0;
    *(f32x4*)(orow + 4) = r1;
}

extern "C" void kernel_launch(void* const* d_in, const int* in_sizes, int n_in,
                              void* d_out, int out_size, void* d_ws, size_t ws_size,
                              hipStream_t stream) {
    const float* x1 = (const float*)d_in[0];
    const float* x2 = (const float*)d_in[1];
    const float* x3 = (const float*)d_in[2];
    const float* x4 = (const float*)d_in[3];
    float* o = (float*)d_out;
    hipLaunchKernelGGL(attn_kernel, dim3(B_ * H_ * (S_ / 32)), dim3(256), 0, stream,
                       x1, x2, x3, x4, o);
}

// Round 6
// 387.948 us; speedup vs baseline: 1.5212x; 1.0777x over previous
//
#include <hip/hip_runtime.h>

#define B_ 2
#define S_ 2048
#define D_ 64
#define H_ 8
#define WAVES 4
#define TPW 16   // t-tiles (of 32) per wave

typedef __bf16 bf16x8 __attribute__((ext_vector_type(8)));
typedef __bf16 bf16x4 __attribute__((ext_vector_type(4)));
typedef float  f32x16 __attribute__((ext_vector_type(16)));
typedef float  f32x4  __attribute__((ext_vector_type(4)));
typedef unsigned int u32x4 __attribute__((ext_vector_type(4)));

// 0.125*log2(e) and log2(e)
#define C_QK 0.18033688011112042f
#define C_B  1.4426950408889634f

__device__ __forceinline__ unsigned int pkbf(float a, float b) {
    __bf16 x = (__bf16)a, y = (__bf16)b;
    unsigned short ux = __builtin_bit_cast(unsigned short, x);
    unsigned short uy = __builtin_bit_cast(unsigned short, y);
    return (unsigned int)ux | ((unsigned int)uy << 16);
}

// no min-waves arg: forcing (256,4) spilled (round 3: 471 MB scratch traffic)
__global__ __launch_bounds__(256) void attn_kernel(
    const float* __restrict__ x1, const float* __restrict__ x2,
    const float* __restrict__ x3, const float* __restrict__ x4,
    float* __restrict__ out)
{
    // smem layout (floats):
    //   [0..8191]    : loop phase = per-wave staging (2048 floats/wave:
    //                  1024 = K tile as bf16 (2048 elems), 1024 = bias f32)
    //                  epilogue phase = sO[w][d][q] combine buffer (aliased)
    //   [8192..8319] : sm[w][32]
    //   [8320..8447] : sl[w][32]
    __shared__ float smem[8448];   // 33792 B -> 4 blocks/CU

    const int tid  = threadIdx.x;
    const int w    = tid >> 6;
    const int lane = tid & 63;
    const int lo = lane & 31;
    const int hi = lane >> 5;

    float*  stg = smem + w * 2048;
    __bf16* kst = (__bf16*)stg;      // K tile, bf16, XOR-swizzled [32 t][64 k]
    float*  bst = stg + 1024;        // bias tile, f32, XOR-swizzled [32 q][32 t]

    const int bid = blockIdx.x;      // 0..1023
    const int b   = bid >> 9;
    const int rem = bid & 511;
    const int h   = rem >> 6;
    const int qt  = rem & 63;
    const int qbase = qt * 32;

    // ---- persistent Q fragments (B-operand of QK mfma) ----
    const float* qrow = x1 + ((size_t)b * S_ + qbase + lo) * D_ + 8 * hi;
    bf16x8 Qf[4];
#pragma unroll
    for (int kk = 0; kk < 4; ++kk) {
        f32x4 qa = *(const f32x4*)(qrow + 16 * kk);
        f32x4 qb = *(const f32x4*)(qrow + 16 * kk + 4);
#pragma unroll
        for (int i = 0; i < 4; ++i) {
            Qf[kk][i]     = (__bf16)qa[i];
            Qf[kk][4 + i] = (__bf16)qb[i];
        }
    }

    // ---- per-wave flash state ----
    f32x16 O0, O1;
#pragma unroll
    for (int i = 0; i < 16; ++i) { O0[i] = 0.f; O1[i] = 0.f; }
    float m_run = -3.0e38f;
    float l_run = 0.f;

    // staging lane constants
    const int krow_w = lane >> 4;    // K write: row = 4j + krow_w
    const int kc4    = lane & 15;    // K write: col granule-of-4
    const int kg8    = kc4 >> 1;     // 8-bf16 granule
    const int khalf  = kc4 & 1;
    const int bq     = lane >> 3;    // bias write: q = 8j + bq
    const int bt4    = lane & 7;     // bias write: 4-float granule

    const float* x3base = x3 + ((size_t)(b * H_ + h) * S_ + qbase) * S_;

    // dense coalesced bias load (8 full lines / inst, rows 8 apart)
    auto load_bias_g = [&](int t, f32x4* dst) {
        const float* base = x3base + t * 32;
#pragma unroll
        for (int j = 0; j < 4; ++j)
            dst[j] = *(const f32x4*)(base + (size_t)(j * 8 + bq) * S_ + 4 * bt4);
    };
    // swizzled LDS write: elem(q, 4*t4+i) at q*32 + 4*(t4^(q&7)) + i
    auto store_bias = [&](const f32x4* src) {
#pragma unroll
        for (int j = 0; j < 4; ++j) {
            int q = j * 8 + bq;
            *(f32x4*)(bst + q * 32 + 4 * (bt4 ^ (q & 7))) = src[j];
        }
    };

    auto mk_pfrag = [&](const float* p) -> bf16x8 {
        int a0 = (int)pkbf(p[0], p[1]), a1 = (int)pkbf(p[2], p[3]);
        int b0 = (int)pkbf(p[4], p[5]), b1 = (int)pkbf(p[6], p[7]);
        int s0 = hi ? a0 : b0, s1 = hi ? a1 : b1;
        int r0 = __shfl_xor(s0, 32);
        int r1 = __shfl_xor(s1, 32);
        u32x4 f;
        f[0] = (unsigned int)(hi ? r0 : a0);
        f[1] = (unsigned int)(hi ? r1 : a1);
        f[2] = (unsigned int)(hi ? b0 : r0);
        f[3] = (unsigned int)(hi ? b1 : r1);
        return __builtin_bit_cast(bf16x8, f);
    };

    const int t0 = w * TPW;
    f32x4 bA[4];
    load_bias_g(t0, bA);

    for (int t = t0; t < t0 + TPW; ++t) {
        const int tb = t * 32;

        // --- V direct loads (coalesced 2 lines/inst), consumed at PV ---
        float vraw[4][8];
#pragma unroll
        for (int g2 = 0; g2 < 2; ++g2) {
#pragma unroll
            for (int dh = 0; dh < 2; ++dh) {
                const float* vb = x4 + ((size_t)b * S_ + tb + 16 * g2 + 8 * hi) * D_ + 32 * dh + lo;
#pragma unroll
                for (int i = 0; i < 8; ++i) vraw[2 * g2 + dh][i] = vb[i * D_];
            }
        }

        // --- K dense load: 8 x 1KB fully-coalesced ---
        const float* kbase = x2 + ((size_t)b * S_ + tb) * D_;
        f32x4 kreg[8];
#pragma unroll
        for (int j = 0; j < 8; ++j)
            kreg[j] = *(const f32x4*)(kbase + j * 256 + lane * 4);

        // --- bias tile t -> LDS (regs loaded last iter); then prefetch t+1 ---
        store_bias(bA);
        {
            int tn = (t + 1 < t0 + TPW) ? t + 1 : t0;
            load_bias_g(tn, bA);
        }

        // --- K -> bf16 -> swizzled LDS: elem(r,c) at r*64 + 8*((c>>3)^(r&7)) + (c&7)
#pragma unroll
        for (int j = 0; j < 8; ++j) {
            bf16x4 kb;
            kb[0] = (__bf16)kreg[j][0]; kb[1] = (__bf16)kreg[j][1];
            kb[2] = (__bf16)kreg[j][2]; kb[3] = (__bf16)kreg[j][3];
            int row = j * 4 + krow_w;
            *(bf16x4*)(kst + row * 64 + 8 * (kg8 ^ (row & 7)) + 4 * khalf) = kb;
        }

        // --- QK^T: A-frag = K[lo][16kk+8hi .. +7] via one swizzled b128 read ---
        f32x16 acc;
#pragma unroll
        for (int i = 0; i < 16; ++i) acc[i] = 0.f;
#pragma unroll
        for (int kk = 0; kk < 4; ++kk) {
            bf16x8 kf = *(const bf16x8*)(kst + lo * 64 + 8 * ((2 * kk + hi) ^ (lo & 7)));
            acc = __builtin_amdgcn_mfma_f32_32x32x16_bf16(kf, Qf[kk], acc, 0, 0, 0);
        }

        // --- bias frags: bias[lo][8g+4hi+{0..3}] via swizzled b128 read ---
        f32x4 rB[4];
#pragma unroll
        for (int g = 0; g < 4; ++g)
            rB[g] = *(const f32x4*)(bst + lo * 32 + 4 * ((2 * g + hi) ^ (lo & 7)));

        // --- softmax (log2 domain) ---
        float s[16];
#pragma unroll
        for (int r = 0; r < 16; ++r)
            s[r] = acc[r] * C_QK + rB[r >> 2][r & 3] * C_B;

        float pmax = s[0];
#pragma unroll
        for (int r = 1; r < 16; ++r) pmax = fmaxf(pmax, s[r]);
        pmax = fmaxf(pmax, __shfl_xor(pmax, 32));

        if (__any(pmax > m_run)) {
            float mnew = fmaxf(m_run, pmax);
            float sc = __builtin_amdgcn_exp2f(m_run - mnew);
#pragma unroll
            for (int r = 0; r < 16; ++r) { O0[r] *= sc; O1[r] *= sc; }
            l_run *= sc;
            m_run = mnew;
        }

        float p[16];
        float ls = 0.f;
#pragma unroll
        for (int r = 0; r < 16; ++r) {
            p[r] = __builtin_amdgcn_exp2f(s[r] - m_run);
            ls += p[r];
        }
        l_run += ls;

        // --- PV: O^T += V^T @ P^T ---
#pragma unroll
        for (int g2 = 0; g2 < 2; ++g2) {
            bf16x8 pf = mk_pfrag(p + 8 * g2);
#pragma unroll
            for (int dh = 0; dh < 2; ++dh) {
                bf16x8 vf;
#pragma unroll
                for (int i = 0; i < 8; ++i) vf[i] = (__bf16)vraw[2 * g2 + dh][i];
                if (dh == 0) O0 = __builtin_amdgcn_mfma_f32_32x32x16_bf16(vf, pf, O0, 0, 0, 0);
                else         O1 = __builtin_amdgcn_mfma_f32_32x32x16_bf16(vf, pf, O1, 0, 0, 0);
            }
        }
    }

    // ---- cross-wave flash combine (sm/sl disjoint from staging) ----
    float l_tot = l_run + __shfl_xor(l_run, 32);
    if (hi == 0) { smem[8192 + w * 32 + lo] = m_run; smem[8320 + w * 32 + lo] = l_tot; }
    __syncthreads();   // after this, staging region is dead -> safe to alias sO

    float M = fmaxf(fmaxf(smem[8192 + lo], smem[8192 + 32 + lo]),
                    fmaxf(smem[8192 + 64 + lo], smem[8192 + 96 + lo]));
    float scale = __builtin_amdgcn_exp2f(m_run - M);
    float Lsum = 0.f;
#pragma unroll
    for (int w2 = 0; w2 < WAVES; ++w2)
        Lsum += smem[8320 + w2 * 32 + lo] * __builtin_amdgcn_exp2f(smem[8192 + w2 * 32 + lo] - M);

    // scaled partial O -> sO[w][d][q] (aliases staging)
    float* sO = smem;
#pragma unroll
    for (int g = 0; g < 4; ++g) {
#pragma unroll
        for (int j = 0; j < 4; ++j) {
            int d = 8 * g + 4 * hi + j;
            sO[(w * D_ + d) * 32 + lo]        = O0[4 * g + j] * scale;
            sO[(w * D_ + d + 32) * 32 + lo]   = O1[4 * g + j] * scale;
        }
    }
    __syncthreads();

    const float inv = 1.0f / Lsum;
    const int d0 = (2 * w + hi) * 8;
    f32x4 r0, r1;
#pragma unroll
    for (int i = 0; i < 4; ++i) {
        float a = sO[(0 * D_ + d0 + i) * 32 + lo] + sO[(1 * D_ + d0 + i) * 32 + lo]
                + sO[(2 * D_ + d0 + i) * 32 + lo] + sO[(3 * D_ + d0 + i) * 32 + lo];
        float c = sO[(0 * D_ + d0 + 4 + i) * 32 + lo] + sO[(1 * D_ + d0 + 4 + i) * 32 + lo]
                + sO[(2 * D_ + d0 + 4 + i) * 32 + lo] + sO[(3 * D_ + d0 + 4 + i) * 32 + lo];
        r0[i] = a * inv;
        r1[i] = c * inv;
    }
    float* orow = out + (((size_t)(b * H_ + h) * S_) + qbase + lo) * D_ + d0;
    *(f32x4*)orow       = r0;
    *(f32x4*)(orow + 4) = r1;
}

extern "C" void kernel_launch(void* const* d_in, const int* in_sizes, int n_in,
                              void* d_out, int out_size, void* d_ws, size_t ws_size,
                              hipStream_t stream) {
    const float* x1 = (const float*)d_in[0];
    const float* x2 = (const float*)d_in[1];
    const float* x3 = (const float*)d_in[2];
    const float* x4 = (const float*)d_in[3];
    float* o = (float*)d_out;
    hipLaunchKernelGGL(attn_kernel, dim3(B_ * H_ * (S_ / 32)), dim3(256), 0, stream,
                       x1, x2, x3, x4, o);
}